// Round 5
// baseline (713.215 us; speedup 1.0000x reference)
//
#include <hip/hip_runtime.h>
#include <hip/hip_bf16.h>

#define T_TOK 4096
#define HIDDEN 3584
#define NQ 28
#define NKV 4
#define HD 128
#define SEQ 1024
#define NQD 3584   // NQ*HD
#define NKVD 512   // NKV*HD
#define QKV_N 4608 // NQD + 2*NKVD

typedef __attribute__((ext_vector_type(8))) short bf16x8;
typedef __attribute__((ext_vector_type(4))) short s16x4;
typedef __attribute__((ext_vector_type(4))) float f32x4;

__device__ __forceinline__ float bf2f(short s) {
  union { unsigned u; float f; } c; c.u = ((unsigned)(unsigned short)s) << 16; return c.f;
}
__device__ __forceinline__ short f2bf(float f) {
  union { float f; unsigned u; } c; c.f = f;
  unsigned u = c.u;
  unsigned r = (u + 0x7FFFu + ((u >> 16) & 1u)) >> 16;
  return (short)r;
}

typedef __attribute__((address_space(1))) const void gvoid;
typedef __attribute__((address_space(3))) void lvoid;
__device__ __forceinline__ void async16(void* l, const void* g) {
  __builtin_amdgcn_global_load_lds((gvoid*)g, (lvoid*)l, 16, 0, 0);
}

// ---------------- prep kernels ----------------

__global__ void cast_hidden(const float* __restrict__ in, short* __restrict__ out, int n4) {
  int i = blockIdx.x * blockDim.x + threadIdx.x;
  if (i >= n4) return;
  float4 v = ((const float4*)in)[i];
  s16x4 o;
  o[0] = f2bf(v.x); o[1] = f2bf(v.y); o[2] = f2bf(v.z); o[3] = f2bf(v.w);
  ((s16x4*)out)[i] = o;
}

__global__ void concat_bias(const float* __restrict__ bq, const float* __restrict__ bk,
                            const float* __restrict__ bv, float* __restrict__ outb) {
  int i = blockIdx.x * blockDim.x + threadIdx.x;
  if (i >= QKV_N) return;
  outb[i] = (i < NQD) ? bq[i] : ((i < NQD + NKVD) ? bk[i - NQD] : bv[i - NQD - NKVD]);
}

// in: fp32 [R, C] row-major -> out: bf16 [C, R] row-major. R,C multiples of 64.
__global__ __launch_bounds__(256) void transpose_cast64(const float* __restrict__ in,
                                                        short* __restrict__ out,
                                                        int R, int C) {
  __shared__ short tile[64][80];  // [c][r], stride 160 B
  int t = threadIdx.x;
  int c0 = blockIdx.x * 64, r0 = blockIdx.y * 64;
  int ty = t >> 4;            // 0..15
  int tx = (t & 15) * 4;      // 0..60
#pragma unroll
  for (int i = 0; i < 4; i++) {
    int r = ty + i * 16;
    float4 v = *(const float4*)&in[(long)(r0 + r) * C + c0 + tx];
    tile[tx + 0][r] = f2bf(v.x);
    tile[tx + 1][r] = f2bf(v.y);
    tile[tx + 2][r] = f2bf(v.z);
    tile[tx + 3][r] = f2bf(v.w);
  }
  __syncthreads();
  int c = t >> 2;             // 0..63
  int rc = (t & 3) * 16;      // 16-short chunk -> two bf16x8 stores
  *(bf16x8*)&out[(long)(c0 + c) * R + r0 + rc]     = *(const bf16x8*)&tile[c][rc];
  *(bf16x8*)&out[(long)(c0 + c) * R + r0 + rc + 8] = *(const bf16x8*)&tile[c][rc + 8];
}

// V transpose: kv_out V-half fp32 [4096 tok][1024, cols 512..1023] ->
// vt_g bf16 [(b*4+h)*128 + d][1024 tok-in-seq]
__global__ __launch_bounds__(256) void vtrans64(const float* __restrict__ kvo,
                                                short* __restrict__ vtg) {
  __shared__ short tile[64][80];
  int t = threadIdx.x;
  int d0 = blockIdx.x * 64;   // 0..511
  int t0 = blockIdx.y * 64;   // token 0..4095 (stays within one seq)
  int b = t0 >> 10;
  int ty = t >> 4, tx = (t & 15) * 4;
#pragma unroll
  for (int i = 0; i < 4; i++) {
    int r = ty + i * 16;
    float4 v = *(const float4*)&kvo[(long)(t0 + r) * 1024 + 512 + d0 + tx];
    tile[tx + 0][r] = f2bf(v.x);
    tile[tx + 1][r] = f2bf(v.y);
    tile[tx + 2][r] = f2bf(v.z);
    tile[tx + 3][r] = f2bf(v.w);
  }
  __syncthreads();
  int d = t >> 2;
  int rc = (t & 3) * 16;
  long ob = (long)(b * 512 + d0 + d) * 1024 + (t0 & 1023) + rc;
  *(bf16x8*)&vtg[ob]     = *(const bf16x8*)&tile[d][rc];
  *(bf16x8*)&vtg[ob + 8] = *(const bf16x8*)&tile[d][rc + 8];
}

// ---------------- GEMM: C[M,N] = A[M,K] @ Bt[N,K]^T (+bias) ----------------
// Single-barrier double-buffered K-loop + XCD-aware rasterization.
// mode 0: fp32 to Cf.  mode 1: Q cols -> bf16 Qo; K cols -> fp32 Kraw; V cols -> fp32 Vout.
__global__ __launch_bounds__(256, 3) void gemm_bt128(
    const short* __restrict__ A, const short* __restrict__ Bt,
    int M, int N, int K,
    const float* __restrict__ bias,
    float* __restrict__ Cf,
    short* __restrict__ Qo, float* __restrict__ Kraw, float* __restrict__ Vout,
    int mode)
{
  __shared__ short lds_a[2][128 * 32];
  __shared__ short lds_b[2][128 * 32];
  int t = threadIdx.x;
  int w = t >> 6;
  int lane = t & 63;
  int ln = lane & 15, qd = lane >> 4;
  int wm = w >> 1, wn = w & 1;

  // XCD-aware raster: dispatch is round-robin over 8 XCDs (pid % 8).
  // Give each XCD a contiguous band of GM/8 M-tiles; n varies fastest inside.
  // Per-XCD A-band = (GM/8)*128 rows * K bf16 (3.5 MB at GM=32,K=3584) fits 4MB L2;
  // B streams once per XCD, served by L3 after the first XCD touches it.
  int GN = N >> 7, GM = M >> 7;       // GM=32 for both GEMMs -> GM/8 = 4
  int pid = blockIdx.x;
  int xcd = pid & 7;
  int local = pid >> 3;               // 0 .. GM/8*GN - 1
  int mloc = local / GN;
  int nti = local - mloc * GN;
  int mti = xcd * (GM >> 3) + mloc;
  int m0 = mti << 7, n0 = nti << 7;

  const short* ga0 = A + (long)(m0 + (t >> 2)) * K + (t & 3) * 8;
  const short* ga1 = ga0 + (long)64 * K;
  const short* gb0 = Bt + (long)(n0 + (t >> 2)) * K + (t & 3) * 8;
  const short* gb1 = gb0 + (long)64 * K;

  f32x4 acc[4][4];
  f32x4 zf = {0.f, 0.f, 0.f, 0.f};
#pragma unroll
  for (int i = 0; i < 4; i++)
#pragma unroll
    for (int j = 0; j < 4; j++) acc[i][j] = zf;

  int niter = K / 32;

  // prologue: stage tile 0 into buffer 0
  {
    char* la = (char*)&lds_a[0][0] + w * 1024;
    char* lb = (char*)&lds_b[0][0] + w * 1024;
    async16(la, ga0);
    async16(la + 4096, ga1);
    async16(lb, gb0);
    async16(lb + 4096, gb1);
    ga0 += 32; ga1 += 32; gb0 += 32; gb1 += 32;
  }

  for (int kt = 0; kt < niter; ++kt) {
    __syncthreads();  // drain: buf[kt&1] ready, buf[kt&1^1] free
    int cur = kt & 1;
    int nxt = cur ^ 1;

    bf16x8 af[4], bfr[4];
#pragma unroll
    for (int i = 0; i < 4; i++)
      af[i] = *(const bf16x8*)&lds_a[cur][(wm * 64 + i * 16 + ln) * 32 + qd * 8];
#pragma unroll
    for (int j = 0; j < 4; j++)
      bfr[j] = *(const bf16x8*)&lds_b[cur][(wn * 64 + j * 16 + ln) * 32 + qd * 8];

    if (kt + 1 < niter) {  // prefetch next tile; completes during MFMA phase
      char* la = (char*)&lds_a[nxt][0] + w * 1024;
      char* lb = (char*)&lds_b[nxt][0] + w * 1024;
      async16(la, ga0);
      async16(la + 4096, ga1);
      async16(lb, gb0);
      async16(lb + 4096, gb1);
      ga0 += 32; ga1 += 32; gb0 += 32; gb1 += 32;
    }

#pragma unroll
    for (int i = 0; i < 4; i++)
#pragma unroll
      for (int j = 0; j < 4; j++)
        acc[i][j] = __builtin_amdgcn_mfma_f32_16x16x32_bf16(af[i], bfr[j], acc[i][j], 0, 0, 0);
  }

  // epilogue — tile-uniform output routing (NQD, NQD+NKVD are multiples of 128)
  if (mode == 0) {
#pragma unroll
    for (int i = 0; i < 4; i++) {
      int grow_base = m0 + wm * 64 + i * 16 + qd * 4;
#pragma unroll
      for (int j = 0; j < 4; j++) {
        int gcol = n0 + wn * 64 + j * 16 + ln;
#pragma unroll
        for (int r = 0; r < 4; r++)
          Cf[(long)(grow_base + r) * N + gcol] = acc[i][j][r];
      }
    }
  } else if (n0 < NQD) {  // Q columns -> bf16
#pragma unroll
    for (int i = 0; i < 4; i++) {
      int grow_base = m0 + wm * 64 + i * 16 + qd * 4;
#pragma unroll
      for (int j = 0; j < 4; j++) {
        int gcol = n0 + wn * 64 + j * 16 + ln;
        float bb = bias[gcol];
#pragma unroll
        for (int r = 0; r < 4; r++)
          Qo[(long)(grow_base + r) * NQD + gcol] = f2bf(acc[i][j][r] + bb);
      }
    }
  } else if (n0 < NQD + NKVD) {  // K columns -> fp32 raw
#pragma unroll
    for (int i = 0; i < 4; i++) {
      int grow_base = m0 + wm * 64 + i * 16 + qd * 4;
#pragma unroll
      for (int j = 0; j < 4; j++) {
        int gcol = n0 + wn * 64 + j * 16 + ln;
        float bb = bias[gcol];
#pragma unroll
        for (int r = 0; r < 4; r++)
          Kraw[(long)(grow_base + r) * 512 + (gcol - NQD)] = acc[i][j][r] + bb;
      }
    }
  } else {  // V columns -> fp32 into kv_fused V half (final output)
#pragma unroll
    for (int i = 0; i < 4; i++) {
      int grow_base = m0 + wm * 64 + i * 16 + qd * 4;
#pragma unroll
      for (int j = 0; j < 4; j++) {
        int gcol = n0 + wn * 64 + j * 16 + ln;
        float bb = bias[gcol];
#pragma unroll
        for (int r = 0; r < 4; r++)
          Vout[(long)(grow_base + r) * 1024 + 512 + (gcol - NQD - NKVD)] = acc[i][j][r] + bb;
      }
    }
  }
}

// ---------------- RoPE + kv_fused (K half) ----------------
__global__ __launch_bounds__(256) void rope_kernel(
    short* __restrict__ qbf, const int* __restrict__ positions,
    const float* __restrict__ kraw, float* __restrict__ kv_out,
    short* __restrict__ kbf)
{
  int t = blockIdx.x;
  float pos = (float)positions[t];
  const float c0 = 19.9315685693241740f / 64.0f; // log2(1e6)/64
  int tid = threadIdx.x;

  for (int p = tid; p < NQ * 64; p += 256) {
    int h = p >> 6, i = p & 63;
    float invf = exp2f(-c0 * (float)i);
    float fr = pos * invf;
    float cs = cosf(fr), sn = sinf(fr);
    long base = (long)t * NQD + h * HD + i;
    float x1 = bf2f(qbf[base]), x2 = bf2f(qbf[base + 64]);
    qbf[base] = f2bf(x1 * cs - x2 * sn);
    qbf[base + 64] = f2bf(x2 * cs + x1 * sn);
  }
  for (int p = tid; p < NKV * 64; p += 256) {
    int h = p >> 6, i = p & 63;
    float invf = exp2f(-c0 * (float)i);
    float fr = pos * invf;
    float cs = cosf(fr), sn = sinf(fr);
    long kbase = (long)t * 512 + h * HD + i;
    float x1 = kraw[kbase], x2 = kraw[kbase + 64];
    float o1 = x1 * cs - x2 * sn, o2 = x2 * cs + x1 * sn;
    long obase = (long)t * 1024 + h * HD + i;
    kv_out[obase] = o1;
    kv_out[obase + 64] = o2;
    kbf[kbase] = f2bf(o1);
    kbf[kbase + 64] = f2bf(o2);
  }
}

// ---------------- Flash attention (causal GQA), XOR-swizzled LDS ----------------
__global__ __launch_bounds__(256, 3) void attn_kernel(
    const short* __restrict__ qbf, const short* __restrict__ kbf,
    const short* __restrict__ vtg, short* __restrict__ attn)
{
  __shared__ short k_lds[64 * 128];
  __shared__ short v_lds[128 * 64];
  __shared__ short p_lds[4 * 16 * 64];

  int t = threadIdx.x;
  int w = t >> 6, lane = t & 63, ln = lane & 15, qd = lane >> 4;
  int qt = 15 - (blockIdx.x & 15);
  int hq = (blockIdx.x >> 4) % NQ;
  int b = blockIdx.x / (16 * NQ);
  int hkv = hq / 7;
  int tq0 = b * SEQ + qt * 64;
  int tb0 = b * SEQ;

  char* kb = (char*)k_lds;
  char* vb = (char*)v_lds;
  char* pbase = (char*)p_lds + w * 2048;

  int krow = t >> 4, kchunk = t & 15;
  int kpos0 = krow * 256 + ((kchunk ^ krow) & 15) * 16;
  int vrow = t >> 3, vchunk = t & 7;
  int vpos0 = vrow * 128 + ((vchunk ^ vrow) & 7) * 16;

  const short* kptr = kbf + (long)(tb0 + krow) * 512 + hkv * 128 + kchunk * 8;
  const short* vptr = vtg + (long)((b * 4 + hkv) * 128 + vrow) * 1024 + vchunk * 8;
  const short* qptr = qbf + (long)(tq0 + krow) * NQD + hq * 128 + kchunk * 8;

  bf16x8 kreg[4], vreg[4], qreg[4];
#pragma unroll
  for (int i = 0; i < 4; i++) {
    qreg[i] = *(const bf16x8*)(qptr + (long)i * 16 * NQD);
    kreg[i] = *(const bf16x8*)(kptr + i * 16 * 512);
    vreg[i] = *(const bf16x8*)(vptr + i * 32 * 1024);
  }
#pragma unroll
  for (int i = 0; i < 4; i++)
    *(bf16x8*)(kb + kpos0 + i * 4096) = qreg[i];
  __syncthreads();

  bf16x8 aq[4];
#pragma unroll
  for (int k2 = 0; k2 < 4; k2++)
    aq[k2] = *(const bf16x8*)(kb + (w * 16 + ln) * 256 + (((k2 * 4 + qd) ^ ln) & 15) * 16);

  f32x4 accO[8];
  f32x4 zf = {0.f, 0.f, 0.f, 0.f};
#pragma unroll
  for (int n = 0; n < 8; n++) accO[n] = zf;
  float m_i[4], l_i[4];
#pragma unroll
  for (int r = 0; r < 4; r++) { m_i[r] = -__builtin_inff(); l_i[r] = 0.f; }

  const float scale = 0.08838834764831845f;

  for (int kt = 0; kt <= qt; ++kt) {
    __syncthreads();
#pragma unroll
    for (int i = 0; i < 4; i++) {
      *(bf16x8*)(kb + kpos0 + i * 4096) = kreg[i];
      *(bf16x8*)(vb + vpos0 + i * 4096) = vreg[i];
    }
    __syncthreads();
    if (kt < qt) {
      kptr += 64 * 512;
      vptr += 64;
#pragma unroll
      for (int i = 0; i < 4; i++) {
        kreg[i] = *(const bf16x8*)(kptr + i * 16 * 512);
        vreg[i] = *(const bf16x8*)(vptr + i * 32 * 1024);
      }
    }

    f32x4 sc[4];
#pragma unroll
    for (int j = 0; j < 4; j++) {
      f32x4 a = zf;
#pragma unroll
      for (int k2 = 0; k2 < 4; k2++) {
        bf16x8 bk = *(const bf16x8*)(kb + (j * 16 + ln) * 256 + (((k2 * 4 + qd) ^ ln) & 15) * 16);
        a = __builtin_amdgcn_mfma_f32_16x16x32_bf16(aq[k2], bk, a, 0, 0, 0);
      }
#pragma unroll
      for (int r = 0; r < 4; r++) a[r] *= scale;
      sc[j] = a;
    }

    if (kt == qt) {
#pragma unroll
      for (int j = 0; j < 4; j++) {
        int kcol = j * 16 + ln;
#pragma unroll
        for (int r = 0; r < 4; r++) {
          int qrow = w * 16 + qd * 4 + r;
          if (kcol > qrow) sc[j][r] = -__builtin_inff();
        }
      }
    }

    float alpha[4], rsum[4];
#pragma unroll
    for (int r = 0; r < 4; r++) {
      float mx = fmaxf(fmaxf(sc[0][r], sc[1][r]), fmaxf(sc[2][r], sc[3][r]));
      mx = fmaxf(mx, __shfl_xor(mx, 1));
      mx = fmaxf(mx, __shfl_xor(mx, 2));
      mx = fmaxf(mx, __shfl_xor(mx, 4));
      mx = fmaxf(mx, __shfl_xor(mx, 8));
      float mnew = fmaxf(m_i[r], mx);
      alpha[r] = __expf(m_i[r] - mnew);
      m_i[r] = mnew;
      rsum[r] = 0.f;
    }
#pragma unroll
    for (int j = 0; j < 4; j++) {
#pragma unroll
      for (int r = 0; r < 4; r++) {
        float p = __expf(sc[j][r] - m_i[r]);
        short pb = f2bf(p);
        rsum[r] += bf2f(pb);
        int row_p = qd * 4 + r;
        *(short*)(pbase + row_p * 128 + (((j * 2 + (ln >> 3)) ^ row_p) & 7) * 16 + (ln & 7) * 2) = pb;
      }
    }
#pragma unroll
    for (int r = 0; r < 4; r++) {
      rsum[r] += __shfl_xor(rsum[r], 1);
      rsum[r] += __shfl_xor(rsum[r], 2);
      rsum[r] += __shfl_xor(rsum[r], 4);
      rsum[r] += __shfl_xor(rsum[r], 8);
      l_i[r] = l_i[r] * alpha[r] + rsum[r];
    }
#pragma unroll
    for (int n = 0; n < 8; n++)
#pragma unroll
      for (int r = 0; r < 4; r++) accO[n][r] *= alpha[r];

    asm volatile("s_waitcnt lgkmcnt(0)" ::: "memory");

    bf16x8 ap0 = *(const bf16x8*)(pbase + ln * 128 + ((qd ^ ln) & 7) * 16);
    bf16x8 ap1 = *(const bf16x8*)(pbase + ln * 128 + (((4 + qd) ^ ln) & 7) * 16);
#pragma unroll
    for (int n = 0; n < 8; n++) {
      bf16x8 bv0 = *(const bf16x8*)(vb + (n * 16 + ln) * 128 + ((qd ^ ln) & 7) * 16);
      bf16x8 bv1 = *(const bf16x8*)(vb + (n * 16 + ln) * 128 + (((4 + qd) ^ ln) & 7) * 16);
      accO[n] = __builtin_amdgcn_mfma_f32_16x16x32_bf16(ap0, bv0, accO[n], 0, 0, 0);
      accO[n] = __builtin_amdgcn_mfma_f32_16x16x32_bf16(ap1, bv1, accO[n], 0, 0, 0);
    }
  }

#pragma unroll
  for (int r = 0; r < 4; r++) {
    float inv = 1.0f / l_i[r];
    int tok = tq0 + w * 16 + qd * 4 + r;
    long base = (long)tok * NQD + hq * HD;
#pragma unroll
    for (int n = 0; n < 8; n++)
      attn[base + n * 16 + ln] = f2bf(accO[n][r] * inv);
  }
}

// ---------------- launch ----------------
extern "C" void kernel_launch(void* const* d_in, const int* in_sizes, int n_in,
                              void* d_out, int out_size, void* d_ws, size_t ws_size,
                              hipStream_t stream) {
  const float* hidden = (const float*)d_in[0];
  const int* positions = (const int*)d_in[1];
  const float* wq = (const float*)d_in[2];
  const float* bq = (const float*)d_in[3];
  const float* wk = (const float*)d_in[4];
  const float* bk = (const float*)d_in[5];
  const float* wv = (const float*)d_in[6];
  const float* bv = (const float*)d_in[7];
  const float* wo = (const float*)d_in[8];

  float* out = (float*)d_out;                       // [T, 3584]
  float* kv_out = out + (long)T_TOK * NQD;          // [T, 1024] (kv_fused)

  char* ws = (char*)d_ws;
  short* hid_bf  = (short*)(ws);                    // T*3584 bf16
  short* wqkvT   = (short*)(ws + 29360128);         // [4608][3584] bf16
  short* woT     = (short*)(ws + 62390272);         // [3584][3584] bf16
  float* biasc   = (float*)(ws + 88080384);         // 4608 f32
  short* q_bf    = (short*)(ws + 88098816);         // T*3584 bf16
  float* kraw    = (float*)(ws + 117458944);        // T*512 f32
  short* k_bf    = (short*)(ws + 125847552);        // T*512 bf16
  short* vt_g    = (short*)(ws + 130041856);        // [16*128][1024] bf16
  short* attn_bf = (short*)(ws + 134236160);        // T*3584 bf16

  cast_hidden<<<(T_TOK * HIDDEN / 4 + 255) / 256, 256, 0, stream>>>(
      hidden, hid_bf, T_TOK * HIDDEN / 4);
  concat_bias<<<(QKV_N + 255) / 256, 256, 0, stream>>>(bq, bk, bv, biasc);
  transpose_cast64<<<dim3(NQD / 64, HIDDEN / 64), 256, 0, stream>>>(wq, wqkvT, HIDDEN, NQD);
  transpose_cast64<<<dim3(NKVD / 64, HIDDEN / 64), 256, 0, stream>>>(
      wk, wqkvT + (long)NQD * HIDDEN, HIDDEN, NKVD);
  transpose_cast64<<<dim3(NKVD / 64, HIDDEN / 64), 256, 0, stream>>>(
      wv, wqkvT + (long)(NQD + NKVD) * HIDDEN, HIDDEN, NKVD);
  transpose_cast64<<<dim3(HIDDEN / 64, NQD / 64), 256, 0, stream>>>(wo, woT, NQD, HIDDEN);

  gemm_bt128<<<(QKV_N / 128) * (T_TOK / 128), 256, 0, stream>>>(
      hid_bf, wqkvT, T_TOK, QKV_N, HIDDEN, biasc, nullptr, q_bf, kraw, kv_out, 1);

  vtrans64<<<dim3(NKVD / 64, T_TOK / 64), 256, 0, stream>>>(kv_out, vt_g);

  rope_kernel<<<T_TOK, 256, 0, stream>>>(q_bf, positions, kraw, kv_out, k_bf);

  attn_kernel<<<4 * NQ * 16, 256, 0, stream>>>(q_bf, k_bf, vt_g, attn_bf);

  gemm_bt128<<<(HIDDEN / 128) * (T_TOK / 128), 256, 0, stream>>>(
      attn_bf, woT, T_TOK, HIDDEN, HIDDEN, nullptr, out, nullptr, nullptr, nullptr, 0);
}